// Round 1
// baseline (673.312 us; speedup 1.0000x reference)
//
#include <hip/hip_runtime.h>
#include <hip/hip_bf16.h>
#include <stdint.h>

// SheafAttention on MI355X (gfx950).
// B=4, T=2048, D=1024, H=16, S=64.
//
// Pipeline:
//  1. absmax of the 6 weight tensors (for exact 6-bit quantization scales)
//  2. quantize + fold: W_all (3072x1024 bf16) = [ (qwu@qwq[h]) ; (qwsv@qwk[h]) ; qwv ]
//     Wo (1024x1024 bf16) = qwo
//  3. GEMM1: x (fp32, cast to bf16 in staging) @ W_all^T -> QKV bf16 (8192x3072)
//  4. flash attention with causal mask + 2-adic bias -> O bf16 (8192x1024)
//  5. GEMM2: O @ Wo^T -> out fp32

typedef __bf16 bf16_t;
typedef __attribute__((ext_vector_type(8))) __bf16 bf16x8;
typedef __attribute__((ext_vector_type(4))) float f32x4;

#define BB 4
#define TT 2048
#define DD 1024
#define HH 16
#define SS 64

__device__ __forceinline__ float quant6(float v, float s) {
    float q = rintf(v / s);                      // round half-to-even, like jnp.round
    q = fminf(fmaxf(q, -31.0f), 31.0f);
    return q * s;
}

// ---------------------------------------------------------------- zero scratch
__global__ void zero_kernel(float* p) {
    if (threadIdx.x < 8) p[threadIdx.x] = 0.0f;
}

// ---------------------------------------------------------------- absmax
__global__ __launch_bounds__(256) void absmax_kernel(const float* __restrict__ src, int n,
                                                     float* __restrict__ out) {
    float m = 0.0f;
    for (int i = blockIdx.x * blockDim.x + threadIdx.x; i < n; i += gridDim.x * blockDim.x)
        m = fmaxf(m, fabsf(src[i]));
    #pragma unroll
    for (int mask = 32; mask > 0; mask >>= 1)
        m = fmaxf(m, __shfl_xor(m, mask));
    __shared__ float red[4];
    int w = threadIdx.x >> 6;
    if ((threadIdx.x & 63) == 0) red[w] = m;
    __syncthreads();
    if (threadIdx.x == 0) {
        m = fmaxf(fmaxf(red[0], red[1]), fmaxf(red[2], red[3]));
        atomicMax((int*)out, __float_as_int(m));   // all values >= 0: int compare is fine
    }
}

// ---------------------------------------------------------------- quantize+cast (wv, wo)
__global__ __launch_bounds__(256) void quant_cast_kernel(const float* __restrict__ src, int n,
                                                         const float* __restrict__ amax, int aidx,
                                                         bf16_t* __restrict__ dst) {
    float s = amax[aidx] / 31.0f + 1e-8f;
    for (int i = blockIdx.x * blockDim.x + threadIdx.x; i < n; i += gridDim.x * blockDim.x)
        dst[i] = (bf16_t)quant6(src[i], s);
}

// ---------------------------------------------------------------- fold stalk map into proj
// out[h*64+i][d] = sum_j q(wsmall[i][j]) * q(wbig[h*64+j][d])
__global__ __launch_bounds__(256) void fold_kernel(const float* __restrict__ wbig,
                                                   const float* __restrict__ wsmall,
                                                   const float* __restrict__ amax,
                                                   int ibig, int ismall,
                                                   bf16_t* __restrict__ outp) {
    int h = blockIdx.x >> 6, i = blockIdx.x & 63;
    int tid = threadIdx.x;
    float sb = amax[ibig] / 31.0f + 1e-8f;
    float ss = amax[ismall] / 31.0f + 1e-8f;
    __shared__ float qu[64];
    if (tid < 64) qu[tid] = quant6(wsmall[i * 64 + tid], ss);
    __syncthreads();
    int d0 = tid * 4;
    float a0 = 0.f, a1 = 0.f, a2 = 0.f, a3 = 0.f;
    for (int j = 0; j < 64; ++j) {
        float u = qu[j];
        float4 w4 = *(const float4*)(wbig + (size_t)(h * 64 + j) * DD + d0);
        a0 += u * quant6(w4.x, sb);
        a1 += u * quant6(w4.y, sb);
        a2 += u * quant6(w4.z, sb);
        a3 += u * quant6(w4.w, sb);
    }
    bf16_t* o = outp + (size_t)(h * 64 + i) * DD + d0;
    o[0] = (bf16_t)a0; o[1] = (bf16_t)a1; o[2] = (bf16_t)a2; o[3] = (bf16_t)a3;
}

// ---------------------------------------------------------------- GEMM  C[M,N] = A[M,K] * Bt[N,K]^T
// 64x64 block tile, 4 waves, each wave does a 16x64 strip with 16x16x32 bf16 MFMA.
template <bool A_F32, bool OUT_F32>
__global__ __launch_bounds__(256) void gemm_bt(const void* __restrict__ Av,
                                               const bf16_t* __restrict__ Bt,
                                               void* __restrict__ Cv,
                                               int lda, int ldb, int ldc, int K) {
    constexpr int LDT = 72;   // +8 bf16 pad: rows land on distinct 4-bank groups (2-way = free)
    __shared__ __align__(16) bf16_t At[64 * LDT];
    __shared__ __align__(16) bf16_t Bs[64 * LDT];
    const int tid = threadIdx.x;
    const int m0 = blockIdx.y * 64;
    const int n0 = blockIdx.x * 64;
    const int w = tid >> 6;
    const int l = tid & 63;
    const int l15 = l & 15;
    const int quad = l >> 4;
    const int q8 = quad * 8;

    f32x4 acc[4];
    #pragma unroll
    for (int c = 0; c < 4; ++c) acc[c] = (f32x4){0.f, 0.f, 0.f, 0.f};

    for (int kc = 0; kc < K; kc += 64) {
        __syncthreads();
        if constexpr (A_F32) {
            const float* A = (const float*)Av;
            int row = tid >> 2;
            int c0 = (tid & 3) * 16;
            const float* src = A + (size_t)(m0 + row) * lda + kc + c0;
            float4 f0 = ((const float4*)src)[0];
            float4 f1 = ((const float4*)src)[1];
            float4 f2 = ((const float4*)src)[2];
            float4 f3 = ((const float4*)src)[3];
            bf16x8 v0, v1;
            v0[0] = (bf16_t)f0.x; v0[1] = (bf16_t)f0.y; v0[2] = (bf16_t)f0.z; v0[3] = (bf16_t)f0.w;
            v0[4] = (bf16_t)f1.x; v0[5] = (bf16_t)f1.y; v0[6] = (bf16_t)f1.z; v0[7] = (bf16_t)f1.w;
            v1[0] = (bf16_t)f2.x; v1[1] = (bf16_t)f2.y; v1[2] = (bf16_t)f2.z; v1[3] = (bf16_t)f2.w;
            v1[4] = (bf16_t)f3.x; v1[5] = (bf16_t)f3.y; v1[6] = (bf16_t)f3.z; v1[7] = (bf16_t)f3.w;
            *(bf16x8*)(At + row * LDT + c0) = v0;
            *(bf16x8*)(At + row * LDT + c0 + 8) = v1;
        } else {
            const bf16_t* A = (const bf16_t*)Av;
            #pragma unroll
            for (int rep = 0; rep < 2; ++rep) {
                int ch = tid + rep * 256;
                int row = ch >> 3, off = (ch & 7) * 8;
                *(bf16x8*)(At + row * LDT + off) =
                    *(const bf16x8*)(A + (size_t)(m0 + row) * lda + kc + off);
            }
        }
        #pragma unroll
        for (int rep = 0; rep < 2; ++rep) {
            int ch = tid + rep * 256;
            int row = ch >> 3, off = (ch & 7) * 8;
            *(bf16x8*)(Bs + row * LDT + off) =
                *(const bf16x8*)(Bt + (size_t)(n0 + row) * ldb + kc + off);
        }
        __syncthreads();
        #pragma unroll
        for (int kb = 0; kb < 64; kb += 32) {
            bf16x8 a = *(const bf16x8*)(At + (w * 16 + l15) * LDT + kb + q8);
            #pragma unroll
            for (int c = 0; c < 4; ++c) {
                bf16x8 bb = *(const bf16x8*)(Bs + (c * 16 + l15) * LDT + kb + q8);
                acc[c] = __builtin_amdgcn_mfma_f32_16x16x32_bf16(a, bb, acc[c], 0, 0, 0);
            }
        }
    }
    // epilogue: C layout col=lane&15, row=quad*4+r
    #pragma unroll
    for (int c = 0; c < 4; ++c) {
        int col = n0 + c * 16 + l15;
        #pragma unroll
        for (int r = 0; r < 4; ++r) {
            int row = m0 + w * 16 + quad * 4 + r;
            if constexpr (OUT_F32)
                ((float*)Cv)[(size_t)row * ldc + col] = acc[c][r];
            else
                ((bf16_t*)Cv)[(size_t)row * ldc + col] = (bf16_t)acc[c][r];
        }
    }
}

// ---------------------------------------------------------------- flash attention
// One block = one (b,h) x 64-row Q tile. 4 waves, wave w owns rows w*16..w*16+15.
__global__ __launch_bounds__(256) void attn_kernel(const bf16_t* __restrict__ QKV,
                                                   const float* __restrict__ p_scale_ptr,
                                                   bf16_t* __restrict__ O) {
    constexpr int LDT = 72;
    __shared__ __align__(16) bf16_t Kt[64 * LDT];   // [k_local][d]
    __shared__ __align__(16) bf16_t Vt[64 * LDT];   // [s][k_local]  (transposed)
    __shared__ __align__(16) bf16_t Pl[4 * 16 * LDT];  // per-wave P scratch

    const int tid = threadIdx.x;
    const int qt = 31 - (blockIdx.x & 31);        // heavy tiles first (load balance)
    const int bh = blockIdx.x >> 5;
    const int b = bh >> 4, h = bh & 15;
    const int w = tid >> 6;
    const int l = tid & 63;
    const int l15 = l & 15;
    const int quad = l >> 4;
    const int q8 = quad * 8;

    const float pscale = p_scale_ptr[0];
    const float scale = 0.125f;                    // 1/sqrt(64)
    const int qbase = qt * 64;
    const size_t rowbase = (size_t)b * TT * 3072;

    // Q A-fragments (row = l15, k-dim chunks of 32)
    const int qrow = qbase + w * 16 + l15;
    const bf16_t* qptr = QKV + rowbase + (size_t)qrow * 3072 + h * 64;
    bf16x8 qa0 = *(const bf16x8*)(qptr + q8);
    bf16x8 qa1 = *(const bf16x8*)(qptr + 32 + q8);

    f32x4 oacc[4];
    #pragma unroll
    for (int c = 0; c < 4; ++c) oacc[c] = (f32x4){0.f, 0.f, 0.f, 0.f};
    float mrun[4], lrun[4];
    #pragma unroll
    for (int r = 0; r < 4; ++r) { mrun[r] = -INFINITY; lrun[r] = 0.f; }

    for (int kbase = 0; kbase <= qbase; kbase += 64) {
        __syncthreads();
        // stage K tile (row-major) — 512 16B chunks, 2 per thread
        #pragma unroll
        for (int rep = 0; rep < 2; ++rep) {
            int ch = tid + rep * 256;
            int row = ch >> 3, off = (ch & 7) * 8;
            *(bf16x8*)(Kt + row * LDT + off) =
                *(const bf16x8*)(QKV + rowbase + (size_t)(kbase + row) * 3072 + 1024 + h * 64 + off);
        }
        // stage V transposed: thread (w,l): s-chunk w*16, k-row l — conflict-free writes
        {
            int s0 = (tid >> 6) * 16, rk = tid & 63;
            const bf16_t* vsrc = QKV + rowbase + (size_t)(kbase + rk) * 3072 + 2048 + h * 64 + s0;
            bf16x8 v0 = *(const bf16x8*)(vsrc);
            bf16x8 v1 = *(const bf16x8*)(vsrc + 8);
            #pragma unroll
            for (int i = 0; i < 8; ++i) {
                Vt[(s0 + i) * LDT + rk] = v0[i];
                Vt[(s0 + 8 + i) * LDT + rk] = v1[i];
            }
        }
        __syncthreads();

        // scores: 16x64 strip per wave
        f32x4 sacc[4];
        #pragma unroll
        for (int c = 0; c < 4; ++c) sacc[c] = (f32x4){0.f, 0.f, 0.f, 0.f};
        #pragma unroll
        for (int c = 0; c < 4; ++c) {
            bf16x8 b0 = *(const bf16x8*)(Kt + (c * 16 + l15) * LDT + q8);
            sacc[c] = __builtin_amdgcn_mfma_f32_16x16x32_bf16(qa0, b0, sacc[c], 0, 0, 0);
            bf16x8 b1 = *(const bf16x8*)(Kt + (c * 16 + l15) * LDT + 32 + q8);
            sacc[c] = __builtin_amdgcn_mfma_f32_16x16x32_bf16(qa1, b1, sacc[c], 0, 0, 0);
        }

        // bias + causal mask + row max
        float sv[4][4];
        float mx[4];
        const int qr0 = qbase + w * 16 + quad * 4;
        #pragma unroll
        for (int r = 0; r < 4; ++r) {
            mx[r] = -INFINITY;
            #pragma unroll
            for (int c = 0; c < 4; ++c) {
                int k = kbase + c * 16 + l15;
                int q = qr0 + r;
                float s;
                if (k > q) {
                    s = -INFINITY;
                } else {
                    int d = q - k;
                    float bias = (d == 0) ? 1.0f : (float)__builtin_ctz(d) * 0.0625f;
                    s = sacc[c][r] * scale + pscale * bias;
                }
                sv[c][r] = s;
                mx[r] = fmaxf(mx[r], s);
            }
        }
        #pragma unroll
        for (int r = 0; r < 4; ++r) {
            #pragma unroll
            for (int mask = 1; mask < 16; mask <<= 1)
                mx[r] = fmaxf(mx[r], __shfl_xor(mx[r], mask));
        }

        float alpha[4], psum[4];
        #pragma unroll
        for (int r = 0; r < 4; ++r) {
            float mn = fmaxf(mrun[r], mx[r]);
            alpha[r] = __expf(mrun[r] - mn);
            mrun[r] = mn;
            psum[r] = 0.f;
        }
        // P = exp(s - m), write to per-wave LDS in C-layout, accumulate row sums
        #pragma unroll
        for (int c = 0; c < 4; ++c) {
            #pragma unroll
            for (int r = 0; r < 4; ++r) {
                float p = __expf(sv[c][r] - mrun[r]);
                psum[r] += p;
                Pl[(w * 16 + quad * 4 + r) * LDT + c * 16 + l15] = (bf16_t)p;
            }
        }
        #pragma unroll
        for (int r = 0; r < 4; ++r) {
            #pragma unroll
            for (int mask = 1; mask < 16; mask <<= 1)
                psum[r] += __shfl_xor(psum[r], mask);
            lrun[r] = lrun[r] * alpha[r] + psum[r];
        }
        #pragma unroll
        for (int c = 0; c < 4; ++c) {
            #pragma unroll
            for (int r = 0; r < 4; ++r) oacc[c][r] *= alpha[r];
        }

        // PV: A = P (per-wave LDS, A-layout read), B = V (from transposed Vt)
        #pragma unroll
        for (int kb = 0; kb < 2; ++kb) {
            bf16x8 pa = *(const bf16x8*)(Pl + (w * 16 + l15) * LDT + kb * 32 + q8);
            #pragma unroll
            for (int sb = 0; sb < 4; ++sb) {
                bf16x8 vb = *(const bf16x8*)(Vt + (sb * 16 + l15) * LDT + kb * 32 + q8);
                oacc[sb] = __builtin_amdgcn_mfma_f32_16x16x32_bf16(pa, vb, oacc[sb], 0, 0, 0);
            }
        }
    }

    // epilogue: normalize and store bf16
    float inv[4];
    #pragma unroll
    for (int r = 0; r < 4; ++r) inv[r] = 1.0f / lrun[r];
    #pragma unroll
    for (int sb = 0; sb < 4; ++sb) {
        #pragma unroll
        for (int r = 0; r < 4; ++r) {
            int q = qbase + w * 16 + quad * 4 + r;
            int col = h * 64 + sb * 16 + l15;
            O[(size_t)(b * TT + q) * DD + col] = (bf16_t)(oacc[sb][r] * inv[r]);
        }
    }
}

// ---------------------------------------------------------------- launch
extern "C" void kernel_launch(void* const* d_in, const int* in_sizes, int n_in,
                              void* d_out, int out_size, void* d_ws, size_t ws_size,
                              hipStream_t stream) {
    const float* x   = (const float*)d_in[0];
    const float* wq  = (const float*)d_in[1];
    const float* wk  = (const float*)d_in[2];
    const float* wv  = (const float*)d_in[3];
    const float* wo  = (const float*)d_in[4];
    const float* wu  = (const float*)d_in[5];
    const float* wsv = (const float*)d_in[6];
    const float* psc = (const float*)d_in[7];
    float* out = (float*)d_out;

    char* ws = (char*)d_ws;
    float*  amax  = (float*)(ws);
    bf16_t* W_all = (bf16_t*)(ws + 256);                                  // 3072x1024 bf16
    bf16_t* Wo    = (bf16_t*)(ws + 256 + 6291456);                        // 1024x1024 bf16
    bf16_t* QKV   = (bf16_t*)(ws + 256 + 6291456 + 2097152);              // 8192x3072 bf16
    bf16_t* Obuf  = (bf16_t*)(ws + 256 + 6291456 + 2097152 + 50331648);   // 8192x1024 bf16

    hipLaunchKernelGGL(zero_kernel, dim3(1), dim3(64), 0, stream, amax);
    hipLaunchKernelGGL(absmax_kernel, dim3(1024), dim3(256), 0, stream, wq, 1048576, amax + 0);
    hipLaunchKernelGGL(absmax_kernel, dim3(1024), dim3(256), 0, stream, wk, 1048576, amax + 1);
    hipLaunchKernelGGL(absmax_kernel, dim3(1024), dim3(256), 0, stream, wv, 1048576, amax + 2);
    hipLaunchKernelGGL(absmax_kernel, dim3(1024), dim3(256), 0, stream, wo, 1048576, amax + 3);
    hipLaunchKernelGGL(absmax_kernel, dim3(16),   dim3(256), 0, stream, wu, 4096,    amax + 4);
    hipLaunchKernelGGL(absmax_kernel, dim3(16),   dim3(256), 0, stream, wsv, 4096,   amax + 5);

    hipLaunchKernelGGL(quant_cast_kernel, dim3(1024), dim3(256), 0, stream,
                       wv, 1048576, amax, 2, W_all + (size_t)2048 * 1024);
    hipLaunchKernelGGL(quant_cast_kernel, dim3(1024), dim3(256), 0, stream,
                       wo, 1048576, amax, 3, Wo);
    hipLaunchKernelGGL(fold_kernel, dim3(1024), dim3(256), 0, stream,
                       wq, wu, amax, 0, 4, W_all);
    hipLaunchKernelGGL(fold_kernel, dim3(1024), dim3(256), 0, stream,
                       wk, wsv, amax, 1, 5, W_all + (size_t)1024 * 1024);

    // GEMM1: QKV = x @ W_all^T   (M=8192, N=3072, K=1024)
    hipLaunchKernelGGL((gemm_bt<true, false>), dim3(48, 128), dim3(256), 0, stream,
                       (const void*)x, W_all, (void*)QKV, 1024, 1024, 3072, 1024);

    // attention
    hipLaunchKernelGGL(attn_kernel, dim3(2048), dim3(256), 0, stream, QKV, psc, Obuf);

    // GEMM2: out = O @ Wo^T   (M=8192, N=1024, K=1024)
    hipLaunchKernelGGL((gemm_bt<false, true>), dim3(16, 128), dim3(256), 0, stream,
                       (const void*)Obuf, Wo, (void*)out, 1024, 1024, 1024, 1024);
}

// Round 2
// 548.358 us; speedup vs baseline: 1.2279x; 1.2279x over previous
//
#include <hip/hip_runtime.h>
#include <hip/hip_bf16.h>
#include <stdint.h>

// SheafAttention on MI355X (gfx950).  B=4, T=2048, D=1024, H=16, S=64.
//
// Pipeline:
//  1. absmax of the 6 weight tensors (one fused launch)
//  2. quantize + fold stalk maps:  W_all (3072x1024 bf16) = [ (qwu@qwq[h]) ; (qwsv@qwk[h]) ; qwv ]
//  3. x -> bf16
//  4. GEMM1 (m97-style 128x128 tile, global_load_lds, XOR swizzle): QKV = xb @ W_all^T
//  5. V transpose -> Vt[bh][s][t]
//  6. barrier-free flash attention (fixed-base softmax, exact after normalization)
//  7. GEMM2: out = O @ Wo^T (fp32 out)

typedef __bf16 bf16_t;
typedef __attribute__((ext_vector_type(8))) __bf16 bf16x8;
typedef __attribute__((ext_vector_type(4))) float f32x4;

#define BB 4
#define TT 2048
#define DD 1024
#define HH 16
#define SS 64

__device__ __forceinline__ float quant6(float v, float s) {
    float q = rintf(v / s);
    q = fminf(fmaxf(q, -31.0f), 31.0f);
    return q * s;
}

__device__ __forceinline__ float fexp2(float x) {
#if __has_builtin(__builtin_amdgcn_exp2f)
    return __builtin_amdgcn_exp2f(x);
#else
    return exp2f(x);
#endif
}

typedef __attribute__((address_space(3))) uint32_t lds_u32;
typedef const __attribute__((address_space(1))) uint32_t glb_u32;

// ---------------------------------------------------------------- zero scratch
__global__ void zero_kernel(float* p) {
    if (threadIdx.x < 8) p[threadIdx.x] = 0.0f;
}

// ---------------------------------------------------------------- fused absmax (6 tensors)
__global__ __launch_bounds__(256) void absmax6(const float* __restrict__ wq,
                                               const float* __restrict__ wk,
                                               const float* __restrict__ wv,
                                               const float* __restrict__ wo,
                                               const float* __restrict__ wu,
                                               const float* __restrict__ wsv,
                                               float* __restrict__ amax) {
    const int t = blockIdx.y;
    const float* src = (t == 0) ? wq : (t == 1) ? wk : (t == 2) ? wv
                     : (t == 3) ? wo : (t == 4) ? wu : wsv;
    const int n4 = (t < 4) ? (1048576 / 4) : (4096 / 4);
    float m = 0.0f;
    for (int i = blockIdx.x * blockDim.x + threadIdx.x; i < n4; i += gridDim.x * blockDim.x) {
        float4 v = ((const float4*)src)[i];
        m = fmaxf(m, fmaxf(fmaxf(fabsf(v.x), fabsf(v.y)), fmaxf(fabsf(v.z), fabsf(v.w))));
    }
    #pragma unroll
    for (int mask = 32; mask > 0; mask >>= 1)
        m = fmaxf(m, __shfl_xor(m, mask));
    __shared__ float red[4];
    int w = threadIdx.x >> 6;
    if ((threadIdx.x & 63) == 0) red[w] = m;
    __syncthreads();
    if (threadIdx.x == 0) {
        m = fmaxf(fmaxf(red[0], red[1]), fmaxf(red[2], red[3]));
        atomicMax((int*)(amax + t), __float_as_int(m));  // values >= 0: int compare ok
    }
}

// ---------------------------------------------------------------- x fp32 -> bf16
__global__ __launch_bounds__(256) void xcvt_kernel(const float* __restrict__ x,
                                                   bf16_t* __restrict__ xb) {
    int i = (blockIdx.x * 256 + threadIdx.x) * 8;
    float4 f0 = *(const float4*)(x + i);
    float4 f1 = *(const float4*)(x + i + 4);
    bf16x8 v;
    v[0] = (bf16_t)f0.x; v[1] = (bf16_t)f0.y; v[2] = (bf16_t)f0.z; v[3] = (bf16_t)f0.w;
    v[4] = (bf16_t)f1.x; v[5] = (bf16_t)f1.y; v[6] = (bf16_t)f1.z; v[7] = (bf16_t)f1.w;
    *(bf16x8*)(xb + i) = v;
}

// ---------------------------------------------------------------- quantize+cast (wv, wo)
__global__ __launch_bounds__(256) void quant_cast_kernel(const float* __restrict__ src, int n,
                                                         const float* __restrict__ amax, int aidx,
                                                         bf16_t* __restrict__ dst) {
    float s = amax[aidx] / 31.0f + 1e-8f;
    for (int i = blockIdx.x * blockDim.x + threadIdx.x; i < n; i += gridDim.x * blockDim.x)
        dst[i] = (bf16_t)quant6(src[i], s);
}

// ---------------------------------------------------------------- fold stalk map into proj
__global__ __launch_bounds__(256) void fold_kernel(const float* __restrict__ wbig,
                                                   const float* __restrict__ wsmall,
                                                   const float* __restrict__ amax,
                                                   int ibig, int ismall,
                                                   bf16_t* __restrict__ outp) {
    int h = blockIdx.x >> 6, i = blockIdx.x & 63;
    int tid = threadIdx.x;
    float sb = amax[ibig] / 31.0f + 1e-8f;
    float ss = amax[ismall] / 31.0f + 1e-8f;
    __shared__ float qu[64];
    if (tid < 64) qu[tid] = quant6(wsmall[i * 64 + tid], ss);
    __syncthreads();
    int d0 = tid * 4;
    float a0 = 0.f, a1 = 0.f, a2 = 0.f, a3 = 0.f;
    for (int j = 0; j < 64; ++j) {
        float u = qu[j];
        float4 w4 = *(const float4*)(wbig + (size_t)(h * 64 + j) * DD + d0);
        a0 += u * quant6(w4.x, sb);
        a1 += u * quant6(w4.y, sb);
        a2 += u * quant6(w4.z, sb);
        a3 += u * quant6(w4.w, sb);
    }
    bf16_t* o = outp + (size_t)(h * 64 + i) * DD + d0;
    o[0] = (bf16_t)a0; o[1] = (bf16_t)a1; o[2] = (bf16_t)a2; o[3] = (bf16_t)a3;
}

// ---------------------------------------------------------------- GEMM  C[M,N] = A[M,K] * Bt[N,K]^T
// m97-style: 128x128 tile, BK=64, 4 waves (each a 64x64 quadrant),
// global_load_lds width=16, XOR-swizzled LDS chunk layout (no padding allowed).
template <bool OUT_F32>
__global__ __launch_bounds__(256) void gemm128(const bf16_t* __restrict__ A,
                                               const bf16_t* __restrict__ Bt,
                                               void* __restrict__ Cv,
                                               int lda, int ldb, int ldc, int K) {
    __shared__ __align__(16) bf16_t As[128 * 64];
    __shared__ __align__(16) bf16_t Bs[128 * 64];
    const int tid = threadIdx.x;
    const int w = tid >> 6, l = tid & 63;
    const int l15 = l & 15, quad = l >> 4;
    const int m0 = blockIdx.y * 128, n0 = blockIdx.x * 128;
    const int wm = (w & 1) * 64, wn = (w >> 1) * 64;

    f32x4 acc[4][4];
    #pragma unroll
    for (int a = 0; a < 4; ++a)
        #pragma unroll
        for (int b = 0; b < 4; ++b) acc[a][b] = (f32x4){0.f, 0.f, 0.f, 0.f};

    for (int kc = 0; kc < K; kc += 64) {
        __syncthreads();
        // stage A and B: 1024 16B chunks each; lane lands at ldsbase + lane*16
        #pragma unroll
        for (int rep = 0; rep < 4; ++rep) {
            int ci = rep * 256 + w * 64 + l;          // chunk id (row*8 + slot)
            int row = ci >> 3, slot = ci & 7;
            int gch = slot ^ (row & 7);               // swizzle: lds slot <- global chunk
            __builtin_amdgcn_global_load_lds(
                (glb_u32*)(A + (size_t)(m0 + row) * lda + kc + gch * 8),
                (lds_u32*)(As + (rep * 256 + w * 64) * 8), 16, 0, 0);
            __builtin_amdgcn_global_load_lds(
                (glb_u32*)(Bt + (size_t)(n0 + row) * ldb + kc + gch * 8),
                (lds_u32*)(Bs + (rep * 256 + w * 64) * 8), 16, 0, 0);
        }
        __syncthreads();
        #pragma unroll
        for (int kb = 0; kb < 2; ++kb) {              // k chunks of 32
            bf16x8 af[4], bf[4];
            #pragma unroll
            for (int mb = 0; mb < 4; ++mb) {
                int row = wm + mb * 16 + l15;
                int slot = ((kb << 2) + quad) ^ (row & 7);
                af[mb] = *(const bf16x8*)(As + (row << 6) + slot * 8);
            }
            #pragma unroll
            for (int nb = 0; nb < 4; ++nb) {
                int row = wn + nb * 16 + l15;
                int slot = ((kb << 2) + quad) ^ (row & 7);
                bf[nb] = *(const bf16x8*)(Bs + (row << 6) + slot * 8);
            }
            #pragma unroll
            for (int mb = 0; mb < 4; ++mb)
                #pragma unroll
                for (int nb = 0; nb < 4; ++nb)
                    acc[mb][nb] = __builtin_amdgcn_mfma_f32_16x16x32_bf16(af[mb], bf[nb], acc[mb][nb], 0, 0, 0);
        }
    }
    // epilogue: C layout col=lane&15, row=quad*4+r
    #pragma unroll
    for (int mb = 0; mb < 4; ++mb) {
        #pragma unroll
        for (int nb = 0; nb < 4; ++nb) {
            int col = n0 + wn + nb * 16 + l15;
            #pragma unroll
            for (int r = 0; r < 4; ++r) {
                int row = m0 + wm + mb * 16 + quad * 4 + r;
                if constexpr (OUT_F32)
                    ((float*)Cv)[(size_t)row * ldc + col] = acc[mb][nb][r];
                else
                    ((bf16_t*)Cv)[(size_t)row * ldc + col] = (bf16_t)acc[mb][nb][r];
            }
        }
    }
}

// ---------------------------------------------------------------- V transpose: QKV V-part -> Vt[bh][s][t]
__global__ __launch_bounds__(256) void vtrans_kernel(const bf16_t* __restrict__ QKV,
                                                     bf16_t* __restrict__ Vt) {
    __shared__ __align__(16) bf16_t tile[64 * 72];    // [s][t_local]
    const int tid = threadIdx.x;
    const int bh = blockIdx.x >> 5, tt = blockIdx.x & 31;
    const int b = bh >> 4, h = bh & 15;
    #pragma unroll
    for (int rep = 0; rep < 2; ++rep) {
        int ci = rep * 256 + tid;
        int row = ci >> 3, ch = ci & 7;               // row = t_local, ch = s chunk
        bf16x8 v = *(const bf16x8*)(QKV + ((size_t)(b * TT + tt * 64 + row)) * 3072 + 2048 + h * 64 + ch * 8);
        #pragma unroll
        for (int j = 0; j < 8; ++j) tile[(ch * 8 + j) * 72 + row] = v[j];
    }
    __syncthreads();
    #pragma unroll
    for (int rep = 0; rep < 2; ++rep) {
        int ci = rep * 256 + tid;
        int s = ci >> 3, ch = ci & 7;
        bf16x8 v = *(const bf16x8*)(tile + s * 72 + ch * 8);
        *(bf16x8*)(Vt + ((size_t)(bh * 64 + s)) * TT + tt * 64 + ch * 8) = v;
    }
}

// ---------------------------------------------------------------- barrier-free flash attention
// One wave owns a 32-row Q strip (2 rowsets of 16). K/V fragments read directly from
// global (L1/L2-served). Fixed-base softmax (m=0): exact after normalization; safe in
// fp32 for this data (overflow needs scores > 115 in log2 domain).
__global__ __launch_bounds__(256, 3) void attn_kernel(const bf16_t* __restrict__ QKV,
                                                      const bf16_t* __restrict__ Vt,
                                                      const float* __restrict__ p_scale_ptr,
                                                      bf16_t* __restrict__ O) {
    constexpr int LDP = 72;
    __shared__ __align__(16) bf16_t Pl[4 * 2 * 16 * LDP];   // per (wave, rowset) P scratch

    const int tid = threadIdx.x;
    const int w = tid >> 6, l = tid & 63;
    const int l15 = l & 15, quad = l >> 4, q8 = quad * 8;
    const int qt = 15 - (blockIdx.x & 15);                  // heavy tiles first
    const int bh = blockIdx.x >> 4;
    const int b = bh >> 4, h = bh & 15;
    const int q0 = qt * 128 + w * 32;

    const float sc2 = 0.125f * 1.44269504089f;              // score scale * log2(e)
    const float pb2 = p_scale_ptr[0] * 1.44269504089f * 0.0625f;  // p_scale*log2e/16
    const size_t xbase = (size_t)b * TT * 3072;
    const bf16_t* Kbase = QKV + xbase + 1024 + h * 64;
    const bf16_t* Vbase = Vt + (size_t)bh * 64 * TT;

    // Q A-fragments
    bf16x8 qa[2][2];
    #pragma unroll
    for (int rs = 0; rs < 2; ++rs)
        #pragma unroll
        for (int kc = 0; kc < 2; ++kc)
            qa[rs][kc] = *(const bf16x8*)(QKV + xbase + (size_t)(q0 + rs * 16 + l15) * 3072 + h * 64 + kc * 32 + q8);

    f32x4 oacc[2][4];
    float lrun[2][4];
    #pragma unroll
    for (int rs = 0; rs < 2; ++rs) {
        #pragma unroll
        for (int sb = 0; sb < 4; ++sb) oacc[rs][sb] = (f32x4){0.f, 0.f, 0.f, 0.f};
        #pragma unroll
        for (int r = 0; r < 4; ++r) lrun[rs][r] = 0.f;
    }

    bf16_t* Plw = Pl + w * 2 * 16 * LDP;
    const int nkt = ((q0 + 31) >> 6) + 1;

    for (int kt = 0; kt < nkt; ++kt) {
        const int kbase = kt * 64;
        // K fragments (B-operand): 8 x 16B global loads
        bf16x8 kb[4][2];
        #pragma unroll
        for (int c = 0; c < 4; ++c)
            #pragma unroll
            for (int kc = 0; kc < 2; ++kc)
                kb[c][kc] = *(const bf16x8*)(Kbase + (size_t)(kbase + c * 16 + l15) * 3072 + kc * 32 + q8);
        // scores
        f32x4 sacc[2][4];
        #pragma unroll
        for (int rs = 0; rs < 2; ++rs)
            #pragma unroll
            for (int c = 0; c < 4; ++c) sacc[rs][c] = (f32x4){0.f, 0.f, 0.f, 0.f};
        #pragma unroll
        for (int rs = 0; rs < 2; ++rs)
            #pragma unroll
            for (int c = 0; c < 4; ++c)
                #pragma unroll
                for (int kc = 0; kc < 2; ++kc)
                    sacc[rs][c] = __builtin_amdgcn_mfma_f32_16x16x32_bf16(qa[rs][kc], kb[c][kc], sacc[rs][c], 0, 0, 0);

        // V fragments (B-operand for PV) — issue early to overlap softmax VALU
        bf16x8 vb[4][2];
        #pragma unroll
        for (int c = 0; c < 4; ++c)
            #pragma unroll
            for (int kc = 0; kc < 2; ++kc)
                vb[c][kc] = *(const bf16x8*)(Vbase + (size_t)(c * 16 + l15) * TT + kbase + kc * 32 + q8);

        // softmax (fixed base): p = 2^(score*log2e), accumulate per-lane partial row sums
        #pragma unroll
        for (int rs = 0; rs < 2; ++rs) {
            const int qr0 = q0 + rs * 16 + quad * 4;
            const bool need_mask = (kbase + 63) > (q0 + rs * 16);
            bf16_t* Pr = Plw + rs * 16 * LDP;
            #pragma unroll
            for (int c = 0; c < 4; ++c) {
                const int k = kbase + c * 16 + l15;
                #pragma unroll
                for (int r = 0; r < 4; ++r) {
                    const int q = qr0 + r;
                    const int d = q - k;
                    float ctzf = (float)__builtin_ctz((unsigned)d | 0x10000u);  // d==0 -> 16 -> bias 1.0
                    float s2 = sacc[rs][c][r] * sc2 + pb2 * ctzf;
                    if (need_mask && k > q) s2 = -INFINITY;
                    float p = fexp2(s2);                                        // exp2(-inf) = 0
                    lrun[rs][r] += p;
                    Pr[(quad * 4 + r) * LDP + c * 16 + l15] = (bf16_t)p;
                }
            }
        }
        __builtin_amdgcn_wave_barrier();   // order LDS P writes before cross-lane frag reads

        // PV
        #pragma unroll
        for (int rs = 0; rs < 2; ++rs) {
            #pragma unroll
            for (int kc = 0; kc < 2; ++kc) {
                bf16x8 pa = *(const bf16x8*)(Plw + rs * 16 * LDP + l15 * LDP + kc * 32 + q8);
                #pragma unroll
                for (int sb = 0; sb < 4; ++sb)
                    oacc[rs][sb] = __builtin_amdgcn_mfma_f32_16x16x32_bf16(pa, vb[sb][kc], oacc[rs][sb], 0, 0, 0);
            }
        }
        __builtin_amdgcn_wave_barrier();   // keep next iter's P writes after these reads
    }

    // epilogue: reduce row sums across the 16-lane groups, normalize, store
    #pragma unroll
    for (int rs = 0; rs < 2; ++rs) {
        float inv[4];
        #pragma unroll
        for (int r = 0; r < 4; ++r) {
            float s = lrun[rs][r];
            s += __shfl_xor(s, 1); s += __shfl_xor(s, 2);
            s += __shfl_xor(s, 4); s += __shfl_xor(s, 8);
            inv[r] = 1.0f / s;
        }
        #pragma unroll
        for (int sb = 0; sb < 4; ++sb) {
            #pragma unroll
            for (int r = 0; r < 4; ++r) {
                int q = q0 + rs * 16 + quad * 4 + r;
                int col = h * 64 + sb * 16 + l15;
                O[(size_t)(b * TT + q) * DD + col] = (bf16_t)(oacc[rs][sb][r] * inv[r]);
            }
        }
    }
}

// ---------------------------------------------------------------- launch
extern "C" void kernel_launch(void* const* d_in, const int* in_sizes, int n_in,
                              void* d_out, int out_size, void* d_ws, size_t ws_size,
                              hipStream_t stream) {
    const float* x   = (const float*)d_in[0];
    const float* wq  = (const float*)d_in[1];
    const float* wk  = (const float*)d_in[2];
    const float* wv  = (const float*)d_in[3];
    const float* wo  = (const float*)d_in[4];
    const float* wu  = (const float*)d_in[5];
    const float* wsv = (const float*)d_in[6];
    const float* psc = (const float*)d_in[7];
    float* out = (float*)d_out;

    char* ws = (char*)d_ws;
    float*  amax  = (float*)(ws);
    bf16_t* W_all = (bf16_t*)(ws + 256);                       // 3072x1024 bf16 (6291456 B)
    bf16_t* Wo    = (bf16_t*)(ws + 6291712);                   // 1024x1024 bf16 (2097152 B)
    bf16_t* xb    = (bf16_t*)(ws + 8388864);                   // 8192x1024 bf16 (16777216 B)
    bf16_t* Obuf  = xb;                                        // reuse: xb dead after GEMM1
    bf16_t* QKV   = (bf16_t*)(ws + 25166080);                  // 8192x3072 bf16 (50331648 B)
    bf16_t* Vt    = (bf16_t*)(ws + 75497728);                  // 64bh x 64s x 2048t bf16 (16777216 B)

    hipLaunchKernelGGL(zero_kernel, dim3(1), dim3(64), 0, stream, amax);
    hipLaunchKernelGGL(absmax6, dim3(64, 6), dim3(256), 0, stream, wq, wk, wv, wo, wu, wsv, amax);
    hipLaunchKernelGGL(xcvt_kernel, dim3(4096), dim3(256), 0, stream, x, xb);
    hipLaunchKernelGGL(quant_cast_kernel, dim3(512), dim3(256), 0, stream,
                       wv, 1048576, amax, 2, W_all + (size_t)2048 * 1024);
    hipLaunchKernelGGL(quant_cast_kernel, dim3(512), dim3(256), 0, stream,
                       wo, 1048576, amax, 3, Wo);
    hipLaunchKernelGGL(fold_kernel, dim3(1024), dim3(256), 0, stream, wq, wu, amax, 0, 4, W_all);
    hipLaunchKernelGGL(fold_kernel, dim3(1024), dim3(256), 0, stream, wk, wsv, amax, 1, 5,
                       W_all + (size_t)1024 * 1024);

    // GEMM1: QKV = xb @ W_all^T   (M=8192, N=3072, K=1024)
    hipLaunchKernelGGL((gemm128<false>), dim3(24, 64), dim3(256), 0, stream,
                       xb, W_all, (void*)QKV, 1024, 1024, 3072, 1024);

    // V transpose
    hipLaunchKernelGGL(vtrans_kernel, dim3(2048), dim3(256), 0, stream, QKV, Vt);

    // attention
    hipLaunchKernelGGL(attn_kernel, dim3(1024), dim3(256), 0, stream, QKV, Vt, psc, Obuf);

    // GEMM2: out = O @ Wo^T   (M=8192, N=1024, K=1024)
    hipLaunchKernelGGL((gemm128<true>), dim3(8, 64), dim3(256), 0, stream,
                       Obuf, Wo, (void*)out, 1024, 1024, 1024, 1024);
}

// Round 3
// 426.090 us; speedup vs baseline: 1.5802x; 1.2870x over previous
//
#include <hip/hip_runtime.h>
#include <hip/hip_bf16.h>
#include <stdint.h>

// SheafAttention on MI355X (gfx950).  B=4, T=2048, D=1024, H=16, S=64.
//
// Pipeline:
//  1. absmax6 (one launch; atomicMax on float bits — 0xAA poison is negative int, safe)
//  2. quant_cast2: wv -> W_all[2048:], wo -> Wo
//  3. fold_mfma: W_all[0:2048] = [ q(wu)@q(wq[h]) ; q(wsv)@q(wk[h]) ] via 16x16x32 MFMA
//  4. xcvt: x -> bf16
//  5. gemm128 (global_load_lds w=16, XOR swizzle incl. bit3): QKV = xb @ W_all^T
//  6. vtrans: V part of QKV -> Vt[bh][s][t]
//  7. attn: work-balanced paired Q-tiles {p, 31-p}, LDS-staged K/V, fixed-base softmax
//  8. gemm128: out = O @ Wo^T (fp32)

typedef __bf16 bf16_t;
typedef __attribute__((ext_vector_type(8))) __bf16 bf16x8;
typedef __attribute__((ext_vector_type(4))) float f32x4;

#define BB 4
#define TT 2048
#define DD 1024
#define HH 16
#define SS 64

__device__ __forceinline__ float quant6(float v, float s) {
    float q = rintf(v / s);
    q = fminf(fmaxf(q, -31.0f), 31.0f);
    return q * s;
}

__device__ __forceinline__ float fexp2(float x) {
#if __has_builtin(__builtin_amdgcn_exp2f)
    return __builtin_amdgcn_exp2f(x);
#else
    return exp2f(x);
#endif
}

typedef __attribute__((address_space(3))) uint32_t lds_u32;
typedef const __attribute__((address_space(1))) uint32_t glb_u32;

// ---------------------------------------------------------------- fused absmax (6 tensors)
__global__ __launch_bounds__(256) void absmax6(const float* __restrict__ wq,
                                               const float* __restrict__ wk,
                                               const float* __restrict__ wv,
                                               const float* __restrict__ wo,
                                               const float* __restrict__ wu,
                                               const float* __restrict__ wsv,
                                               float* __restrict__ amax) {
    const int t = blockIdx.y;
    const float* src = (t == 0) ? wq : (t == 1) ? wk : (t == 2) ? wv
                     : (t == 3) ? wo : (t == 4) ? wu : wsv;
    const int n4 = (t < 4) ? (1048576 / 4) : (4096 / 4);
    float m = 0.0f;
    for (int i = blockIdx.x * blockDim.x + threadIdx.x; i < n4; i += gridDim.x * blockDim.x) {
        float4 v = ((const float4*)src)[i];
        m = fmaxf(m, fmaxf(fmaxf(fabsf(v.x), fabsf(v.y)), fmaxf(fabsf(v.z), fabsf(v.w))));
    }
    #pragma unroll
    for (int mask = 32; mask > 0; mask >>= 1)
        m = fmaxf(m, __shfl_xor(m, mask));
    __shared__ float red[4];
    int w = threadIdx.x >> 6;
    if ((threadIdx.x & 63) == 0) red[w] = m;
    __syncthreads();
    if (threadIdx.x == 0) {
        m = fmaxf(fmaxf(red[0], red[1]), fmaxf(red[2], red[3]));
        // amax is poisoned 0xAAAAAAAA (negative as int); result bits are positive -> max works
        atomicMax((int*)(amax + t), __float_as_int(m));
    }
}

// ---------------------------------------------------------------- x fp32 -> bf16
__global__ __launch_bounds__(256) void xcvt_kernel(const float* __restrict__ x,
                                                   bf16_t* __restrict__ xb) {
    int i = (blockIdx.x * 256 + threadIdx.x) * 8;
    float4 f0 = *(const float4*)(x + i);
    float4 f1 = *(const float4*)(x + i + 4);
    bf16x8 v;
    v[0] = (bf16_t)f0.x; v[1] = (bf16_t)f0.y; v[2] = (bf16_t)f0.z; v[3] = (bf16_t)f0.w;
    v[4] = (bf16_t)f1.x; v[5] = (bf16_t)f1.y; v[6] = (bf16_t)f1.z; v[7] = (bf16_t)f1.w;
    *(bf16x8*)(xb + i) = v;
}

// ---------------------------------------------------------------- quantize+cast wv & wo (one launch)
__global__ __launch_bounds__(256) void quant_cast2(const float* __restrict__ wv,
                                                   const float* __restrict__ wo,
                                                   const float* __restrict__ amax,
                                                   bf16_t* __restrict__ dv,
                                                   bf16_t* __restrict__ dw) {
    const int which = blockIdx.y;
    const float* src = which ? wo : wv;
    bf16_t* dst = which ? dw : dv;
    float s = amax[which ? 3 : 2] / 31.0f + 1e-8f;
    int i = (blockIdx.x * 256 + threadIdx.x) * 8;
    float4 f0 = *(const float4*)(src + i);
    float4 f1 = *(const float4*)(src + i + 4);
    bf16x8 v;
    v[0] = (bf16_t)quant6(f0.x, s); v[1] = (bf16_t)quant6(f0.y, s);
    v[2] = (bf16_t)quant6(f0.z, s); v[3] = (bf16_t)quant6(f0.w, s);
    v[4] = (bf16_t)quant6(f1.x, s); v[5] = (bf16_t)quant6(f1.y, s);
    v[6] = (bf16_t)quant6(f1.z, s); v[7] = (bf16_t)quant6(f1.w, s);
    *(bf16x8*)(dst + i) = v;
}

// ---------------------------------------------------------------- fold via MFMA
// out[h*64+i][d] = sum_j q(wsml[i][j]) * q(wbig[h*64+j][d]); block=(h,64-col slice), wave=m-block
__global__ __launch_bounds__(256) void fold_mfma(const float* __restrict__ wq,
                                                 const float* __restrict__ wk,
                                                 const float* __restrict__ wu,
                                                 const float* __restrict__ wsv,
                                                 const float* __restrict__ amax,
                                                 bf16_t* __restrict__ W_all) {
    const int which = blockIdx.y;
    const float* wbig = which ? wk : wq;
    const float* wsml = which ? wsv : wu;
    const float sb = amax[which ? 1 : 0] / 31.0f + 1e-8f;
    const float ss = amax[which ? 5 : 4] / 31.0f + 1e-8f;
    bf16_t* outp = W_all + (size_t)which * 1024 * 1024;
    const int h = blockIdx.x >> 4, n0 = (blockIdx.x & 15) * 64;
    const int w = threadIdx.x >> 6, l = threadIdx.x & 63;
    const int l15 = l & 15, quad = l >> 4, q8 = quad * 8;
    const int m0 = w * 16;

    bf16x8 af[2];
    #pragma unroll
    for (int kc = 0; kc < 2; ++kc) {
        const float* src = wsml + (m0 + l15) * 64 + kc * 32 + q8;
        float4 f0 = *(const float4*)(src);
        float4 f1 = *(const float4*)(src + 4);
        bf16x8 a;
        a[0] = (bf16_t)quant6(f0.x, ss); a[1] = (bf16_t)quant6(f0.y, ss);
        a[2] = (bf16_t)quant6(f0.z, ss); a[3] = (bf16_t)quant6(f0.w, ss);
        a[4] = (bf16_t)quant6(f1.x, ss); a[5] = (bf16_t)quant6(f1.y, ss);
        a[6] = (bf16_t)quant6(f1.z, ss); a[7] = (bf16_t)quant6(f1.w, ss);
        af[kc] = a;
    }
    f32x4 acc[4];
    #pragma unroll
    for (int nb = 0; nb < 4; ++nb) acc[nb] = (f32x4){0.f, 0.f, 0.f, 0.f};
    #pragma unroll
    for (int kc = 0; kc < 2; ++kc) {
        #pragma unroll
        for (int nb = 0; nb < 4; ++nb) {
            bf16x8 bfr;
            #pragma unroll
            for (int j = 0; j < 8; ++j)
                bfr[j] = (bf16_t)quant6(wbig[(size_t)(h * 64 + kc * 32 + q8 + j) * 1024 + n0 + nb * 16 + l15], sb);
            acc[nb] = __builtin_amdgcn_mfma_f32_16x16x32_bf16(af[kc], bfr, acc[nb], 0, 0, 0);
        }
    }
    #pragma unroll
    for (int nb = 0; nb < 4; ++nb)
        #pragma unroll
        for (int r = 0; r < 4; ++r)
            outp[(size_t)(h * 64 + m0 + quad * 4 + r) * 1024 + n0 + nb * 16 + l15] = (bf16_t)acc[nb][r];
}

// ---------------------------------------------------------------- GEMM  C[M,N] = A[M,K] * Bt[N,K]^T
// 128x128 tile, BK=64, global_load_lds w=16, XOR swizzle incl. row bit3 (<=2-way LDS).
template <bool OUT_F32>
__global__ __launch_bounds__(256) void gemm128(const bf16_t* __restrict__ A,
                                               const bf16_t* __restrict__ Bt,
                                               void* __restrict__ Cv,
                                               int lda, int ldb, int ldc, int K) {
    __shared__ __align__(16) bf16_t As[128 * 64];
    __shared__ __align__(16) bf16_t Bs[128 * 64];
    const int tid = threadIdx.x;
    const int w = tid >> 6, l = tid & 63;
    const int l15 = l & 15, quad = l >> 4;
    const int m0 = blockIdx.y * 128, n0 = blockIdx.x * 128;
    const int wm = (w & 1) * 64, wn = (w >> 1) * 64;

    f32x4 acc[4][4];
    #pragma unroll
    for (int a = 0; a < 4; ++a)
        #pragma unroll
        for (int b = 0; b < 4; ++b) acc[a][b] = (f32x4){0.f, 0.f, 0.f, 0.f};

    for (int kc = 0; kc < K; kc += 64) {
        __syncthreads();
        #pragma unroll
        for (int rep = 0; rep < 4; ++rep) {
            int ci = rep * 256 + w * 64 + l;
            int row = ci >> 3, slot = ci & 7;
            int gch = slot ^ ((row ^ (row >> 3)) & 7);
            __builtin_amdgcn_global_load_lds(
                (glb_u32*)(A + (size_t)(m0 + row) * lda + kc + gch * 8),
                (lds_u32*)(As + (rep * 256 + w * 64) * 8), 16, 0, 0);
            __builtin_amdgcn_global_load_lds(
                (glb_u32*)(Bt + (size_t)(n0 + row) * ldb + kc + gch * 8),
                (lds_u32*)(Bs + (rep * 256 + w * 64) * 8), 16, 0, 0);
        }
        __syncthreads();
        #pragma unroll
        for (int kb = 0; kb < 2; ++kb) {
            bf16x8 af[4], bfr[4];
            #pragma unroll
            for (int mb = 0; mb < 4; ++mb) {
                int row = wm + mb * 16 + l15;
                int slot = ((kb << 2) + quad) ^ ((row ^ (row >> 3)) & 7);
                af[mb] = *(const bf16x8*)(As + (row << 6) + slot * 8);
            }
            #pragma unroll
            for (int nb = 0; nb < 4; ++nb) {
                int row = wn + nb * 16 + l15;
                int slot = ((kb << 2) + quad) ^ ((row ^ (row >> 3)) & 7);
                bfr[nb] = *(const bf16x8*)(Bs + (row << 6) + slot * 8);
            }
            #pragma unroll
            for (int mb = 0; mb < 4; ++mb)
                #pragma unroll
                for (int nb = 0; nb < 4; ++nb)
                    acc[mb][nb] = __builtin_amdgcn_mfma_f32_16x16x32_bf16(af[mb], bfr[nb], acc[mb][nb], 0, 0, 0);
        }
    }
    #pragma unroll
    for (int mb = 0; mb < 4; ++mb) {
        #pragma unroll
        for (int nb = 0; nb < 4; ++nb) {
            int col = n0 + wn + nb * 16 + l15;
            #pragma unroll
            for (int r = 0; r < 4; ++r) {
                int row = m0 + wm + mb * 16 + quad * 4 + r;
                if constexpr (OUT_F32)
                    ((float*)Cv)[(size_t)row * ldc + col] = acc[mb][nb][r];
                else
                    ((bf16_t*)Cv)[(size_t)row * ldc + col] = (bf16_t)acc[mb][nb][r];
            }
        }
    }
}

// ---------------------------------------------------------------- V transpose: QKV V-part -> Vt[bh][s][t]
__global__ __launch_bounds__(256) void vtrans_kernel(const bf16_t* __restrict__ QKV,
                                                     bf16_t* __restrict__ Vt) {
    __shared__ __align__(16) bf16_t tile[64 * 72];
    const int tid = threadIdx.x;
    const int bh = blockIdx.x >> 5, tt = blockIdx.x & 31;
    const int b = bh >> 4, h = bh & 15;
    #pragma unroll
    for (int rep = 0; rep < 2; ++rep) {
        int ci = rep * 256 + tid;
        int row = ci >> 3, ch = ci & 7;
        bf16x8 v = *(const bf16x8*)(QKV + ((size_t)(b * TT + tt * 64 + row)) * 3072 + 2048 + h * 64 + ch * 8);
        #pragma unroll
        for (int j = 0; j < 8; ++j) tile[(ch * 8 + j) * 72 + row] = v[j];
    }
    __syncthreads();
    #pragma unroll
    for (int rep = 0; rep < 2; ++rep) {
        int ci = rep * 256 + tid;
        int s = ci >> 3, ch = ci & 7;
        bf16x8 v = *(const bf16x8*)(tile + s * 72 + ch * 8);
        *(bf16x8*)(Vt + ((size_t)(bh * 64 + s)) * TT + tt * 64 + ch * 8) = v;
    }
}

// ---------------------------------------------------------------- attention
__device__ __forceinline__ void attn_step(const bf16_t* __restrict__ Ks,
                                          const bf16_t* __restrict__ Vs,
                                          bf16_t* __restrict__ Pw, int rsel,
                                          const bf16x8* qa, f32x4* oacc, float* lrun,
                                          int q0, int kbase, bool diag,
                                          float sc2, float pb2,
                                          int l15, int quad, int q8) {
    f32x4 sacc[4];
    #pragma unroll
    for (int c = 0; c < 4; ++c) sacc[c] = (f32x4){0.f, 0.f, 0.f, 0.f};
    #pragma unroll
    for (int kc = 0; kc < 2; ++kc) {
        #pragma unroll
        for (int c = 0; c < 4; ++c) {
            int row = c * 16 + l15;
            int slot = (kc * 4 + quad) ^ ((row ^ (row >> 3)) & 7);
            bf16x8 kb = *(const bf16x8*)(Ks + row * 64 + slot * 8);
            sacc[c] = __builtin_amdgcn_mfma_f32_16x16x32_bf16(qa[kc], kb, sacc[c], 0, 0, 0);
        }
    }
    const int qr0 = q0 + quad * 4;
    #pragma unroll
    for (int c = 0; c < 4; ++c) {
        const int k = kbase + c * 16 + l15;
        const int ch = c * 2 + (l15 >> 3);
        #pragma unroll
        for (int r = 0; r < 4; ++r) {
            const int q = qr0 + r;
            const int d = q - k;
            float ctzf = (float)__builtin_ctz((unsigned)d | 0x10000u);  // d==0 -> 16 -> bias 1.0
            float s2 = sacc[c][r] * sc2 + pb2 * ctzf;
            if (diag && k > q) s2 = -INFINITY;
            float p = fexp2(s2);
            lrun[r] += p;
            int prow = rsel * 16 + quad * 4 + r;
            int slot = ch ^ ((prow ^ (prow >> 3)) & 7);
            Pw[prow * 64 + slot * 8 + (l15 & 7)] = (bf16_t)p;
        }
    }
    __builtin_amdgcn_wave_barrier();
    #pragma unroll
    for (int kc = 0; kc < 2; ++kc) {
        int prow = rsel * 16 + l15;
        int pslot = (kc * 4 + quad) ^ ((prow ^ (prow >> 3)) & 7);
        bf16x8 pa = *(const bf16x8*)(Pw + prow * 64 + pslot * 8);
        #pragma unroll
        for (int sb = 0; sb < 4; ++sb) {
            int vrow = sb * 16 + l15;
            int vslot = (kc * 4 + quad) ^ ((vrow ^ (vrow >> 3)) & 7);
            bf16x8 vb = *(const bf16x8*)(Vs + vrow * 64 + vslot * 8);
            oacc[sb] = __builtin_amdgcn_mfma_f32_16x16x32_bf16(pa, vb, oacc[sb], 0, 0, 0);
        }
    }
    __builtin_amdgcn_wave_barrier();
}

// Block = (bh, pair): Q-tiles {pair, 31-pair} (64 rows each) -> exactly 33 tile-iters/block.
__global__ __launch_bounds__(256, 4) void attn_kernel(const bf16_t* __restrict__ QKV,
                                                      const bf16_t* __restrict__ Vt,
                                                      const float* __restrict__ p_scale_ptr,
                                                      bf16_t* __restrict__ O) {
    __shared__ __align__(16) bf16_t Ks[64 * 64];
    __shared__ __align__(16) bf16_t Vs[64 * 64];
    __shared__ __align__(16) bf16_t Ps[4 * 32 * 64];

    const int tid = threadIdx.x;
    const int w = tid >> 6, l = tid & 63;
    const int l15 = l & 15, quad = l >> 4, q8 = quad * 8;
    const int pair = blockIdx.x & 15;
    const int bh = blockIdx.x >> 4;
    const int b = bh >> 4, h = bh & 15;
    const int qtA = pair, qtB = 31 - pair;
    const int q0A = qtA * 64 + w * 16, q0B = qtB * 64 + w * 16;

    const float sc2 = 0.125f * 1.44269504089f;
    const float pb2 = p_scale_ptr[0] * 1.44269504089f * 0.0625f;
    const size_t xbase = (size_t)b * TT * 3072;

    bf16x8 qaA[2], qaB[2];
    #pragma unroll
    for (int kc = 0; kc < 2; ++kc) {
        qaA[kc] = *(const bf16x8*)(QKV + xbase + (size_t)(q0A + l15) * 3072 + h * 64 + kc * 32 + q8);
        qaB[kc] = *(const bf16x8*)(QKV + xbase + (size_t)(q0B + l15) * 3072 + h * 64 + kc * 32 + q8);
    }

    f32x4 oA[4], oB[4];
    float lA[4], lB[4];
    #pragma unroll
    for (int i = 0; i < 4; ++i) {
        oA[i] = (f32x4){0.f, 0.f, 0.f, 0.f};
        oB[i] = (f32x4){0.f, 0.f, 0.f, 0.f};
        lA[i] = 0.f; lB[i] = 0.f;
    }
    bf16_t* Pw = Ps + w * 2048;

    for (int kt = 0; kt <= qtB; ++kt) {
        const int kbase = kt * 64;
        __syncthreads();
        #pragma unroll
        for (int rep = 0; rep < 2; ++rep) {
            int ci = rep * 256 + tid;
            int row = ci >> 3, slot = ci & 7;
            int gch = slot ^ ((row ^ (row >> 3)) & 7);
            __builtin_amdgcn_global_load_lds(
                (glb_u32*)(QKV + xbase + (size_t)(kbase + row) * 3072 + 1024 + h * 64 + gch * 8),
                (lds_u32*)(Ks + (rep * 256 + w * 64) * 8), 16, 0, 0);
            __builtin_amdgcn_global_load_lds(
                (glb_u32*)(Vt + (size_t)bh * 131072 + (size_t)row * 2048 + kbase + gch * 8),
                (lds_u32*)(Vs + (rep * 256 + w * 64) * 8), 16, 0, 0);
        }
        __syncthreads();
        attn_step(Ks, Vs, Pw, 1, qaB, oB, lB, q0B, kbase, kt == qtB, sc2, pb2, l15, quad, q8);
        if (kt <= qtA)
            attn_step(Ks, Vs, Pw, 0, qaA, oA, lA, q0A, kbase, kt == qtA, sc2, pb2, l15, quad, q8);
    }

    // epilogue: reduce row sums across 16-lane groups, normalize, store both tiles
    #pragma unroll
    for (int t = 0; t < 2; ++t) {
        float* lr = t ? lB : lA;
        f32x4* oo = t ? oB : oA;
        int q0 = t ? q0B : q0A;
        float inv[4];
        #pragma unroll
        for (int r = 0; r < 4; ++r) {
            float s = lr[r];
            s += __shfl_xor(s, 1); s += __shfl_xor(s, 2);
            s += __shfl_xor(s, 4); s += __shfl_xor(s, 8);
            inv[r] = 1.0f / s;
        }
        #pragma unroll
        for (int sb = 0; sb < 4; ++sb) {
            #pragma unroll
            for (int r = 0; r < 4; ++r) {
                int q = q0 + quad * 4 + r;
                int col = h * 64 + sb * 16 + l15;
                O[(size_t)(b * TT + q) * DD + col] = (bf16_t)(oo[sb][r] * inv[r]);
            }
        }
    }
}

// ---------------------------------------------------------------- launch
extern "C" void kernel_launch(void* const* d_in, const int* in_sizes, int n_in,
                              void* d_out, int out_size, void* d_ws, size_t ws_size,
                              hipStream_t stream) {
    const float* x   = (const float*)d_in[0];
    const float* wq  = (const float*)d_in[1];
    const float* wk  = (const float*)d_in[2];
    const float* wv  = (const float*)d_in[3];
    const float* wo  = (const float*)d_in[4];
    const float* wu  = (const float*)d_in[5];
    const float* wsv = (const float*)d_in[6];
    const float* psc = (const float*)d_in[7];
    float* out = (float*)d_out;

    char* ws = (char*)d_ws;
    float*  amax  = (float*)(ws);
    bf16_t* W_all = (bf16_t*)(ws + 256);                       // 3072x1024 bf16 (6291456 B)
    bf16_t* Wo    = (bf16_t*)(ws + 6291712);                   // 1024x1024 bf16 (2097152 B)
    bf16_t* xb    = (bf16_t*)(ws + 8388864);                   // 8192x1024 bf16 (16777216 B)
    bf16_t* Obuf  = xb;                                        // reuse: xb dead after GEMM1
    bf16_t* QKV   = (bf16_t*)(ws + 25166080);                  // 8192x3072 bf16 (50331648 B)
    bf16_t* Vt    = (bf16_t*)(ws + 75497728);                  // 64bh x 64s x 2048t bf16

    hipLaunchKernelGGL(absmax6, dim3(64, 6), dim3(256), 0, stream, wq, wk, wv, wo, wu, wsv, amax);
    hipLaunchKernelGGL(quant_cast2, dim3(512, 2), dim3(256), 0, stream,
                       wv, wo, amax, W_all + (size_t)2048 * 1024, Wo);
    hipLaunchKernelGGL(fold_mfma, dim3(256, 2), dim3(256), 0, stream, wq, wk, wu, wsv, amax, W_all);
    hipLaunchKernelGGL(xcvt_kernel, dim3(4096), dim3(256), 0, stream, x, xb);

    // GEMM1: QKV = xb @ W_all^T   (M=8192, N=3072, K=1024)
    hipLaunchKernelGGL((gemm128<false>), dim3(24, 64), dim3(256), 0, stream,
                       xb, W_all, (void*)QKV, 1024, 1024, 3072, 1024);

    // V transpose
    hipLaunchKernelGGL(vtrans_kernel, dim3(2048), dim3(256), 0, stream, QKV, Vt);

    // attention (1024 balanced blocks)
    hipLaunchKernelGGL(attn_kernel, dim3(1024), dim3(256), 0, stream, QKV, Vt, psc, Obuf);

    // GEMM2: out = O @ Wo^T   (M=8192, N=1024, K=1024)
    hipLaunchKernelGGL((gemm128<true>), dim3(8, 64), dim3(256), 0, stream,
                       Obuf, Wo, (void*)out, 1024, 1024, 1024, 1024);
}

// Round 4
// 297.258 us; speedup vs baseline: 2.2651x; 1.4334x over previous
//
#include <hip/hip_runtime.h>
#include <hip/hip_bf16.h>
#include <stdint.h>

// SheafAttention on MI355X (gfx950).  B=4, T=2048, D=1024, H=16, S=64.
//
// Pipeline:
//  1. absmax6 (one launch; atomicMax on float bits — 0xAA poison is negative int, safe)
//  2. quant_cast2: wv -> W_all[2048:], wo -> Wo
//  3. fold_mfma: W_all[0:2048] = [ q(wu)@q(wq[h]) * 0.125*log2e ; q(wsv)@q(wk[h]) ]
//  4. xcvt: x -> bf16
//  5. gemm128 (global_load_lds w=16, XOR swizzle): QKV = xb @ W_all^T
//  6. vtrans: V part of QKV -> Vt[bh][s][t]
//  7. attn: XCD-local paired Q-tiles {p, 31-p}; K/V frags shared across both tiles
//  8. gemm128: out = O @ Wo^T (fp32)

typedef __bf16 bf16_t;
typedef __attribute__((ext_vector_type(8))) __bf16 bf16x8;
typedef __attribute__((ext_vector_type(4))) float f32x4;

#define BB 4
#define TT 2048
#define DD 1024
#define HH 16
#define SS 64

__device__ __forceinline__ float quant6(float v, float s) {
    float q = rintf(v / s);
    q = fminf(fmaxf(q, -31.0f), 31.0f);
    return q * s;
}

__device__ __forceinline__ float fexp2(float x) {
#if __has_builtin(__builtin_amdgcn_exp2f)
    return __builtin_amdgcn_exp2f(x);
#else
    return exp2f(x);
#endif
}

typedef __attribute__((address_space(3))) uint32_t lds_u32;
typedef const __attribute__((address_space(1))) uint32_t glb_u32;

// ---------------------------------------------------------------- fused absmax (6 tensors)
__global__ __launch_bounds__(256) void absmax6(const float* __restrict__ wq,
                                               const float* __restrict__ wk,
                                               const float* __restrict__ wv,
                                               const float* __restrict__ wo,
                                               const float* __restrict__ wu,
                                               const float* __restrict__ wsv,
                                               float* __restrict__ amax) {
    const int t = blockIdx.y;
    const float* src = (t == 0) ? wq : (t == 1) ? wk : (t == 2) ? wv
                     : (t == 3) ? wo : (t == 4) ? wu : wsv;
    const int n4 = (t < 4) ? (1048576 / 4) : (4096 / 4);
    float m = 0.0f;
    for (int i = blockIdx.x * blockDim.x + threadIdx.x; i < n4; i += gridDim.x * blockDim.x) {
        float4 v = ((const float4*)src)[i];
        m = fmaxf(m, fmaxf(fmaxf(fabsf(v.x), fabsf(v.y)), fmaxf(fabsf(v.z), fabsf(v.w))));
    }
    #pragma unroll
    for (int mask = 32; mask > 0; mask >>= 1)
        m = fmaxf(m, __shfl_xor(m, mask));
    __shared__ float red[4];
    int w = threadIdx.x >> 6;
    if ((threadIdx.x & 63) == 0) red[w] = m;
    __syncthreads();
    if (threadIdx.x == 0) {
        m = fmaxf(fmaxf(red[0], red[1]), fmaxf(red[2], red[3]));
        atomicMax((int*)(amax + t), __float_as_int(m));
    }
}

// ---------------------------------------------------------------- x fp32 -> bf16
__global__ __launch_bounds__(256) void xcvt_kernel(const float* __restrict__ x,
                                                   bf16_t* __restrict__ xb) {
    int i = (blockIdx.x * 256 + threadIdx.x) * 8;
    float4 f0 = *(const float4*)(x + i);
    float4 f1 = *(const float4*)(x + i + 4);
    bf16x8 v;
    v[0] = (bf16_t)f0.x; v[1] = (bf16_t)f0.y; v[2] = (bf16_t)f0.z; v[3] = (bf16_t)f0.w;
    v[4] = (bf16_t)f1.x; v[5] = (bf16_t)f1.y; v[6] = (bf16_t)f1.z; v[7] = (bf16_t)f1.w;
    *(bf16x8*)(xb + i) = v;
}

// ---------------------------------------------------------------- quantize+cast wv & wo
__global__ __launch_bounds__(256) void quant_cast2(const float* __restrict__ wv,
                                                   const float* __restrict__ wo,
                                                   const float* __restrict__ amax,
                                                   bf16_t* __restrict__ dv,
                                                   bf16_t* __restrict__ dw) {
    const int which = blockIdx.y;
    const float* src = which ? wo : wv;
    bf16_t* dst = which ? dw : dv;
    float s = amax[which ? 3 : 2] / 31.0f + 1e-8f;
    int i = (blockIdx.x * 256 + threadIdx.x) * 8;
    float4 f0 = *(const float4*)(src + i);
    float4 f1 = *(const float4*)(src + i + 4);
    bf16x8 v;
    v[0] = (bf16_t)quant6(f0.x, s); v[1] = (bf16_t)quant6(f0.y, s);
    v[2] = (bf16_t)quant6(f0.z, s); v[3] = (bf16_t)quant6(f0.w, s);
    v[4] = (bf16_t)quant6(f1.x, s); v[5] = (bf16_t)quant6(f1.y, s);
    v[6] = (bf16_t)quant6(f1.z, s); v[7] = (bf16_t)quant6(f1.w, s);
    *(bf16x8*)(dst + i) = v;
}

// ---------------------------------------------------------------- fold via MFMA
// Q-part (which==0) is pre-scaled by 0.125*log2(e) so attention softmax needs no mul.
__global__ __launch_bounds__(256) void fold_mfma(const float* __restrict__ wq,
                                                 const float* __restrict__ wk,
                                                 const float* __restrict__ wu,
                                                 const float* __restrict__ wsv,
                                                 const float* __restrict__ amax,
                                                 bf16_t* __restrict__ W_all) {
    const int which = blockIdx.y;
    const float* wbig = which ? wk : wq;
    const float* wsml = which ? wsv : wu;
    const float sb = amax[which ? 1 : 0] / 31.0f + 1e-8f;
    const float ss = amax[which ? 5 : 4] / 31.0f + 1e-8f;
    const float oscale = which ? 1.0f : 0.125f * 1.44269504089f;
    bf16_t* outp = W_all + (size_t)which * 1024 * 1024;
    const int h = blockIdx.x >> 4, n0 = (blockIdx.x & 15) * 64;
    const int w = threadIdx.x >> 6, l = threadIdx.x & 63;
    const int l15 = l & 15, quad = l >> 4, q8 = quad * 8;
    const int m0 = w * 16;

    bf16x8 af[2];
    #pragma unroll
    for (int kc = 0; kc < 2; ++kc) {
        const float* src = wsml + (m0 + l15) * 64 + kc * 32 + q8;
        float4 f0 = *(const float4*)(src);
        float4 f1 = *(const float4*)(src + 4);
        bf16x8 a;
        a[0] = (bf16_t)quant6(f0.x, ss); a[1] = (bf16_t)quant6(f0.y, ss);
        a[2] = (bf16_t)quant6(f0.z, ss); a[3] = (bf16_t)quant6(f0.w, ss);
        a[4] = (bf16_t)quant6(f1.x, ss); a[5] = (bf16_t)quant6(f1.y, ss);
        a[6] = (bf16_t)quant6(f1.z, ss); a[7] = (bf16_t)quant6(f1.w, ss);
        af[kc] = a;
    }
    f32x4 acc[4];
    #pragma unroll
    for (int nb = 0; nb < 4; ++nb) acc[nb] = (f32x4){0.f, 0.f, 0.f, 0.f};
    #pragma unroll
    for (int kc = 0; kc < 2; ++kc) {
        #pragma unroll
        for (int nb = 0; nb < 4; ++nb) {
            bf16x8 bfr;
            #pragma unroll
            for (int j = 0; j < 8; ++j)
                bfr[j] = (bf16_t)quant6(wbig[(size_t)(h * 64 + kc * 32 + q8 + j) * 1024 + n0 + nb * 16 + l15], sb);
            acc[nb] = __builtin_amdgcn_mfma_f32_16x16x32_bf16(af[kc], bfr, acc[nb], 0, 0, 0);
        }
    }
    #pragma unroll
    for (int nb = 0; nb < 4; ++nb)
        #pragma unroll
        for (int r = 0; r < 4; ++r)
            outp[(size_t)(h * 64 + m0 + quad * 4 + r) * 1024 + n0 + nb * 16 + l15] =
                (bf16_t)(acc[nb][r] * oscale);
}

// ---------------------------------------------------------------- GEMM  C[M,N] = A[M,K] * Bt[N,K]^T
template <bool OUT_F32>
__global__ __launch_bounds__(256) void gemm128(const bf16_t* __restrict__ A,
                                               const bf16_t* __restrict__ Bt,
                                               void* __restrict__ Cv,
                                               int lda, int ldb, int ldc, int K) {
    __shared__ __align__(16) bf16_t As[128 * 64];
    __shared__ __align__(16) bf16_t Bs[128 * 64];
    const int tid = threadIdx.x;
    const int w = tid >> 6, l = tid & 63;
    const int l15 = l & 15, quad = l >> 4;
    const int m0 = blockIdx.y * 128, n0 = blockIdx.x * 128;
    const int wm = (w & 1) * 64, wn = (w >> 1) * 64;

    f32x4 acc[4][4];
    #pragma unroll
    for (int a = 0; a < 4; ++a)
        #pragma unroll
        for (int b = 0; b < 4; ++b) acc[a][b] = (f32x4){0.f, 0.f, 0.f, 0.f};

    for (int kc = 0; kc < K; kc += 64) {
        __syncthreads();
        #pragma unroll
        for (int rep = 0; rep < 4; ++rep) {
            int ci = rep * 256 + w * 64 + l;
            int row = ci >> 3, slot = ci & 7;
            int gch = slot ^ ((row ^ (row >> 3)) & 7);
            __builtin_amdgcn_global_load_lds(
                (glb_u32*)(A + (size_t)(m0 + row) * lda + kc + gch * 8),
                (lds_u32*)(As + (rep * 256 + w * 64) * 8), 16, 0, 0);
            __builtin_amdgcn_global_load_lds(
                (glb_u32*)(Bt + (size_t)(n0 + row) * ldb + kc + gch * 8),
                (lds_u32*)(Bs + (rep * 256 + w * 64) * 8), 16, 0, 0);
        }
        __syncthreads();
        #pragma unroll
        for (int kb = 0; kb < 2; ++kb) {
            bf16x8 af[4], bfr[4];
            #pragma unroll
            for (int mb = 0; mb < 4; ++mb) {
                int row = wm + mb * 16 + l15;
                int slot = ((kb << 2) + quad) ^ ((row ^ (row >> 3)) & 7);
                af[mb] = *(const bf16x8*)(As + (row << 6) + slot * 8);
            }
            #pragma unroll
            for (int nb = 0; nb < 4; ++nb) {
                int row = wn + nb * 16 + l15;
                int slot = ((kb << 2) + quad) ^ ((row ^ (row >> 3)) & 7);
                bfr[nb] = *(const bf16x8*)(Bs + (row << 6) + slot * 8);
            }
            #pragma unroll
            for (int mb = 0; mb < 4; ++mb)
                #pragma unroll
                for (int nb = 0; nb < 4; ++nb)
                    acc[mb][nb] = __builtin_amdgcn_mfma_f32_16x16x32_bf16(af[mb], bfr[nb], acc[mb][nb], 0, 0, 0);
        }
    }
    #pragma unroll
    for (int mb = 0; mb < 4; ++mb) {
        #pragma unroll
        for (int nb = 0; nb < 4; ++nb) {
            int col = n0 + wn + nb * 16 + l15;
            #pragma unroll
            for (int r = 0; r < 4; ++r) {
                int row = m0 + wm + mb * 16 + quad * 4 + r;
                if constexpr (OUT_F32)
                    ((float*)Cv)[(size_t)row * ldc + col] = acc[mb][nb][r];
                else
                    ((bf16_t*)Cv)[(size_t)row * ldc + col] = (bf16_t)acc[mb][nb][r];
            }
        }
    }
}

// ---------------------------------------------------------------- V transpose: QKV V-part -> Vt[bh][s][t]
__global__ __launch_bounds__(256) void vtrans_kernel(const bf16_t* __restrict__ QKV,
                                                     bf16_t* __restrict__ Vt) {
    __shared__ __align__(16) bf16_t tile[64 * 72];
    const int tid = threadIdx.x;
    const int bh = blockIdx.x >> 5, tt = blockIdx.x & 31;
    const int b = bh >> 4, h = bh & 15;
    #pragma unroll
    for (int rep = 0; rep < 2; ++rep) {
        int ci = rep * 256 + tid;
        int row = ci >> 3, ch = ci & 7;
        bf16x8 v = *(const bf16x8*)(QKV + ((size_t)(b * TT + tt * 64 + row)) * 3072 + 2048 + h * 64 + ch * 8);
        #pragma unroll
        for (int j = 0; j < 8; ++j) tile[(ch * 8 + j) * 72 + row] = v[j];
    }
    __syncthreads();
    #pragma unroll
    for (int rep = 0; rep < 2; ++rep) {
        int ci = rep * 256 + tid;
        int s = ci >> 3, ch = ci & 7;
        bf16x8 v = *(const bf16x8*)(tile + s * 72 + ch * 8);
        *(bf16x8*)(Vt + ((size_t)(bh * 64 + s)) * TT + tt * 64 + ch * 8) = v;
    }
}

// ---------------------------------------------------------------- attention
// One softmax+PV step for one 64-row Q tile, using pre-loaded K/V fragments.
__device__ __forceinline__ void attn_step(bf16_t* __restrict__ Pw, int rsel,
                                          const bf16x8 kb[4][2], const bf16x8 vb[4][2],
                                          const bf16x8 qa[2],
                                          f32x4* oacc, float* lrun,
                                          int q0, int kbase, bool diag, float pb2,
                                          int l15, int quad) {
    f32x4 sacc[4];
    #pragma unroll
    for (int c = 0; c < 4; ++c) sacc[c] = (f32x4){0.f, 0.f, 0.f, 0.f};
    #pragma unroll
    for (int kc = 0; kc < 2; ++kc)
        #pragma unroll
        for (int c = 0; c < 4; ++c)
            sacc[c] = __builtin_amdgcn_mfma_f32_16x16x32_bf16(qa[kc], kb[c][kc], sacc[c], 0, 0, 0);

    const int qr0 = q0 + quad * 4;
    #pragma unroll
    for (int c = 0; c < 4; ++c) {
        const int k = kbase + c * 16 + l15;
        const int ch = c * 2 + (l15 >> 3);
        #pragma unroll
        for (int r = 0; r < 4; ++r) {
            const int q = qr0 + r;
            const int d = q - k;
            float ctzf = (float)__builtin_ctz((unsigned)d | 0x10000u);  // d==0 -> 16 -> bias 1.0
            float s2 = sacc[c][r] + pb2 * ctzf;                          // Q pre-scaled by 0.125*log2e
            if (diag && k > q) s2 = -INFINITY;
            float p = fexp2(s2);
            lrun[r] += p;
            int prow = rsel * 16 + quad * 4 + r;
            int slot = ch ^ ((prow ^ (prow >> 3)) & 7);
            Pw[prow * 64 + slot * 8 + (l15 & 7)] = (bf16_t)p;
        }
    }
    __builtin_amdgcn_wave_barrier();
    #pragma unroll
    for (int kc = 0; kc < 2; ++kc) {
        int prow = rsel * 16 + l15;
        int pslot = (kc * 4 + quad) ^ ((prow ^ (prow >> 3)) & 7);
        bf16x8 pa = *(const bf16x8*)(Pw + prow * 64 + pslot * 8);
        #pragma unroll
        for (int sb = 0; sb < 4; ++sb)
            oacc[sb] = __builtin_amdgcn_mfma_f32_16x16x32_bf16(pa, vb[sb][kc], oacc[sb], 0, 0, 0);
    }
    __builtin_amdgcn_wave_barrier();
}

// Block = (bh, pair): Q-tiles {pair, 31-pair}. XCD-aware decode: all 16 pair-blocks of a bh
// share blockIdx%8 (same XCD L2) and sit in one 128-block dispatch window (co-resident).
__global__ __launch_bounds__(256, 2) void attn_kernel(const bf16_t* __restrict__ QKV,
                                                      const bf16_t* __restrict__ Vt,
                                                      const float* __restrict__ p_scale_ptr,
                                                      bf16_t* __restrict__ O) {
    __shared__ __align__(16) bf16_t Ks[64 * 64];
    __shared__ __align__(16) bf16_t Vs[64 * 64];
    __shared__ __align__(16) bf16_t Ps[4 * 32 * 64];

    const int tid = threadIdx.x;
    const int w = tid >> 6, l = tid & 63;
    const int l15 = l & 15, quad = l >> 4, q8 = quad * 8;
    const int pair = (blockIdx.x >> 3) & 15;
    const int bh = (blockIdx.x & 7) + ((blockIdx.x >> 7) << 3);
    const int b = bh >> 4, h = bh & 15;
    const int qtA = pair, qtB = 31 - pair;
    const int q0A = qtA * 64 + w * 16, q0B = qtB * 64 + w * 16;

    const float pb2 = p_scale_ptr[0] * 1.44269504089f * 0.0625f;
    const size_t xbase = (size_t)b * TT * 3072;

    bf16x8 qaA[2], qaB[2];
    #pragma unroll
    for (int kc = 0; kc < 2; ++kc) {
        qaA[kc] = *(const bf16x8*)(QKV + xbase + (size_t)(q0A + l15) * 3072 + h * 64 + kc * 32 + q8);
        qaB[kc] = *(const bf16x8*)(QKV + xbase + (size_t)(q0B + l15) * 3072 + h * 64 + kc * 32 + q8);
    }

    f32x4 oA[4], oB[4];
    float lA[4], lB[4];
    #pragma unroll
    for (int i = 0; i < 4; ++i) {
        oA[i] = (f32x4){0.f, 0.f, 0.f, 0.f};
        oB[i] = (f32x4){0.f, 0.f, 0.f, 0.f};
        lA[i] = 0.f; lB[i] = 0.f;
    }
    bf16_t* Pw = Ps + w * 2048;

    for (int kt = 0; kt <= qtB; ++kt) {
        const int kbase = kt * 64;
        __syncthreads();
        #pragma unroll
        for (int rep = 0; rep < 2; ++rep) {
            int ci = rep * 256 + tid;
            int row = ci >> 3, slot = ci & 7;
            int gch = slot ^ ((row ^ (row >> 3)) & 7);
            __builtin_amdgcn_global_load_lds(
                (glb_u32*)(QKV + xbase + (size_t)(kbase + row) * 3072 + 1024 + h * 64 + gch * 8),
                (lds_u32*)(Ks + (rep * 256 + w * 64) * 8), 16, 0, 0);
            __builtin_amdgcn_global_load_lds(
                (glb_u32*)(Vt + (size_t)bh * 131072 + (size_t)row * 2048 + kbase + gch * 8),
                (lds_u32*)(Vs + (rep * 256 + w * 64) * 8), 16, 0, 0);
        }
        __syncthreads();
        // K/V fragments once per k-tile, shared by both Q-tiles
        bf16x8 kb[4][2], vb[4][2];
        #pragma unroll
        for (int kc = 0; kc < 2; ++kc) {
            #pragma unroll
            for (int c = 0; c < 4; ++c) {
                int row = c * 16 + l15;
                int slot = (kc * 4 + quad) ^ ((row ^ (row >> 3)) & 7);
                kb[c][kc] = *(const bf16x8*)(Ks + row * 64 + slot * 8);
                vb[c][kc] = *(const bf16x8*)(Vs + row * 64 + slot * 8);
            }
        }
        attn_step(Pw, 1, kb, vb, qaB, oB, lB, q0B, kbase, kt == qtB, pb2, l15, quad);
        if (kt <= qtA)
            attn_step(Pw, 0, kb, vb, qaA, oA, lA, q0A, kbase, kt == qtA, pb2, l15, quad);
    }

    // epilogue
    #pragma unroll
    for (int t = 0; t < 2; ++t) {
        float* lr = t ? lB : lA;
        f32x4* oo = t ? oB : oA;
        int q0 = t ? q0B : q0A;
        float inv[4];
        #pragma unroll
        for (int r = 0; r < 4; ++r) {
            float s = lr[r];
            s += __shfl_xor(s, 1); s += __shfl_xor(s, 2);
            s += __shfl_xor(s, 4); s += __shfl_xor(s, 8);
            inv[r] = 1.0f / s;
        }
        #pragma unroll
        for (int sb = 0; sb < 4; ++sb) {
            #pragma unroll
            for (int r = 0; r < 4; ++r) {
                int q = q0 + quad * 4 + r;
                int col = h * 64 + sb * 16 + l15;
                O[(size_t)(b * TT + q) * DD + col] = (bf16_t)(oo[sb][r] * inv[r]);
            }
        }
    }
}

// ---------------------------------------------------------------- launch
extern "C" void kernel_launch(void* const* d_in, const int* in_sizes, int n_in,
                              void* d_out, int out_size, void* d_ws, size_t ws_size,
                              hipStream_t stream) {
    const float* x   = (const float*)d_in[0];
    const float* wq  = (const float*)d_in[1];
    const float* wk  = (const float*)d_in[2];
    const float* wv  = (const float*)d_in[3];
    const float* wo  = (const float*)d_in[4];
    const float* wu  = (const float*)d_in[5];
    const float* wsv = (const float*)d_in[6];
    const float* psc = (const float*)d_in[7];
    float* out = (float*)d_out;

    char* ws = (char*)d_ws;
    float*  amax  = (float*)(ws);
    bf16_t* W_all = (bf16_t*)(ws + 256);                       // 3072x1024 bf16 (6291456 B)
    bf16_t* Wo    = (bf16_t*)(ws + 6291712);                   // 1024x1024 bf16 (2097152 B)
    bf16_t* xb    = (bf16_t*)(ws + 8388864);                   // 8192x1024 bf16 (16777216 B)
    bf16_t* Obuf  = xb;                                        // reuse: xb dead after GEMM1
    bf16_t* QKV   = (bf16_t*)(ws + 25166080);                  // 8192x3072 bf16 (50331648 B)
    bf16_t* Vt    = (bf16_t*)(ws + 75497728);                  // 64bh x 64s x 2048t bf16

    hipLaunchKernelGGL(absmax6, dim3(64, 6), dim3(256), 0, stream, wq, wk, wv, wo, wu, wsv, amax);
    hipLaunchKernelGGL(quant_cast2, dim3(512, 2), dim3(256), 0, stream,
                       wv, wo, amax, W_all + (size_t)2048 * 1024, Wo);
    hipLaunchKernelGGL(fold_mfma, dim3(256, 2), dim3(256), 0, stream, wq, wk, wu, wsv, amax, W_all);
    hipLaunchKernelGGL(xcvt_kernel, dim3(4096), dim3(256), 0, stream, x, xb);

    // GEMM1: QKV = xb @ W_all^T   (M=8192, N=3072, K=1024)
    hipLaunchKernelGGL((gemm128<false>), dim3(24, 64), dim3(256), 0, stream,
                       xb, W_all, (void*)QKV, 1024, 1024, 3072, 1024);

    // V transpose
    hipLaunchKernelGGL(vtrans_kernel, dim3(2048), dim3(256), 0, stream, QKV, Vt);

    // attention (1024 blocks, XCD-swizzled)
    hipLaunchKernelGGL(attn_kernel, dim3(1024), dim3(256), 0, stream, QKV, Vt, psc, Obuf);

    // GEMM2: out = O @ Wo^T   (M=8192, N=1024, K=1024)
    hipLaunchKernelGGL((gemm128<true>), dim3(8, 64), dim3(256), 0, stream,
                       Obuf, Wo, (void*)out, 1024, 1024, 1024, 1024);
}